// Round 3
// baseline (1763.216 us; speedup 1.0000x reference)
//
#include <hip/hip_runtime.h>
#include <hip/hip_bf16.h>

// B=4, S=4096, D=512, FH=2048, H=64
// outputs: progress (B*S) ++ forecast (B*S) ++ fore (B*S*D), all f32

#if __has_builtin(__builtin_amdgcn_exp2f)
__device__ __forceinline__ float EXP2(float x) { return __builtin_amdgcn_exp2f(x); }
#else
__device__ __forceinline__ float EXP2(float x) { return __expf(x * 0.6931471805599453f); }
#endif
#if __has_builtin(__builtin_amdgcn_rcpf)
__device__ __forceinline__ float RCPF(float x) { return __builtin_amdgcn_rcpf(x); }
#else
__device__ __forceinline__ float RCPF(float x) { return 1.0f / x; }
#endif

__device__ __forceinline__ float fsig(float x) { return 1.0f / (1.0f + __expf(-x)); }
__device__ __forceinline__ float ftanh(float x) { return 1.0f - 2.0f / (1.0f + __expf(2.0f * x)); }

// Wave64 sum via DPP row_shr 1/2/4/8 + row_bcast15/31; full sum lands in lane 63.
__device__ __forceinline__ float dpp_sum64_lane63(float x) {
    x += __int_as_float(__builtin_amdgcn_update_dpp(0, __float_as_int(x), 0x111, 0xf, 0xf, true));
    x += __int_as_float(__builtin_amdgcn_update_dpp(0, __float_as_int(x), 0x112, 0xf, 0xf, true));
    x += __int_as_float(__builtin_amdgcn_update_dpp(0, __float_as_int(x), 0x114, 0xf, 0xf, true));
    x += __int_as_float(__builtin_amdgcn_update_dpp(0, __float_as_int(x), 0x118, 0xf, 0xf, true));
    x += __int_as_float(__builtin_amdgcn_update_dpp(0, __float_as_int(x), 0x142, 0xf, 0xf, true));
    x += __int_as_float(__builtin_amdgcn_update_dpp(0, __float_as_int(x), 0x143, 0xf, 0xf, true));
    return x;
}
__device__ __forceinline__ float readlane63(float x) {
    return __int_as_float(__builtin_amdgcn_readlane(__float_as_int(x), 63));
}

// ---------------------------------------------------------------------------
// 64x64 f32 tile core (BK=16): fills acc[4][4] for tile (bm,bn).
//   BT=true : B is [N][K] row-major  -> C = A @ B^T
//   BT=false: B is [K][N] row-major  -> C = A @ B
// Caller provides shared buffers and zeroed acc; caller stores the result.
// ---------------------------------------------------------------------------
template<bool BT>
__device__ void gemm_tile_acc(const float* __restrict__ A, const float* __restrict__ B,
                              int K, int N, int bm, int bn,
                              float (* __restrict__ As)[68], float (* __restrict__ Bs)[68],
                              float acc[4][4])
{
    const int tid = threadIdx.x;
    const int tx = tid & 15, ty = tid >> 4;
    for (int k0 = 0; k0 < K; k0 += 16) {
        {
            const int r = tid >> 2, cc = (tid & 3) * 4;
            const float4 av = *reinterpret_cast<const float4*>(
                &A[(size_t)(bm + r) * K + k0 + cc]);
            As[cc + 0][r] = av.x; As[cc + 1][r] = av.y;
            As[cc + 2][r] = av.z; As[cc + 3][r] = av.w;
        }
        if (BT) {
            const int r = tid >> 2, cc = (tid & 3) * 4;
            const float4 bv = *reinterpret_cast<const float4*>(
                &B[(size_t)(bn + r) * K + k0 + cc]);
            Bs[cc + 0][r] = bv.x; Bs[cc + 1][r] = bv.y;
            Bs[cc + 2][r] = bv.z; Bs[cc + 3][r] = bv.w;
        } else {
            const int r = tid >> 4, cc = (tid & 15) * 4;
            const float4 bv = *reinterpret_cast<const float4*>(
                &B[(size_t)(k0 + r) * N + bn + cc]);
            Bs[r][cc + 0] = bv.x; Bs[r][cc + 1] = bv.y;
            Bs[r][cc + 2] = bv.z; Bs[r][cc + 3] = bv.w;
        }
        __syncthreads();
        #pragma unroll
        for (int k = 0; k < 16; ++k) {
            float a[4], b[4];
            #pragma unroll
            for (int i = 0; i < 4; ++i) a[i] = As[k][ty * 4 + i];
            #pragma unroll
            for (int j = 0; j < 4; ++j) b[j] = Bs[k][tx * 4 + j];
            #pragma unroll
            for (int i = 0; i < 4; ++i)
                #pragma unroll
                for (int j = 0; j < 4; ++j)
                    acc[i][j] = fmaf(a[i], b[j], acc[i][j]);
        }
        __syncthreads();
    }
}

// ---------------------------------------------------------------------------
// prep: blocks [0,64) Weff = W2@W1 ; [64,72) beff = W2@b1+b2 ; [72,328) Gx = x[0]@Wih^T
// ---------------------------------------------------------------------------
__global__ __launch_bounds__(256) void prep_kernel(
    const float* __restrict__ x, const float* __restrict__ W1,
    const float* __restrict__ b1, const float* __restrict__ W2,
    const float* __restrict__ b2, const float* __restrict__ Wih,
    float* __restrict__ Weff, float* __restrict__ beff, float* __restrict__ Gx)
{
    __shared__ float As[16][68], Bs[16][68];
    const int bid = blockIdx.x;
    const int tx = threadIdx.x & 15, ty = threadIdx.x >> 4;

    if (bid < 64) {                       // Weff: M=N=512, K=2048, B=[K][N]
        const int bm = (bid >> 3) * 64, bn = (bid & 7) * 64;
        float acc[4][4] = {};
        gemm_tile_acc<false>(W2, W1, 2048, 512, bm, bn, As, Bs, acc);
        #pragma unroll
        for (int i = 0; i < 4; ++i)
            #pragma unroll
            for (int j = 0; j < 4; ++j)
                Weff[(size_t)(bm + ty * 4 + i) * 512 + bn + tx * 4 + j] = acc[i][j];
    } else if (bid < 72) {                // beff: 64 outputs per block, 16 per wave
        const int w = threadIdx.x >> 6, j = threadIdx.x & 63;
        const int base = (bid - 64) * 64 + w * 16;
        for (int o = 0; o < 16; ++o) {
            const int i = base + o;
            float s = 0.0f;
            #pragma unroll
            for (int m = 0; m < 32; ++m)
                s = fmaf(W2[(size_t)i * 2048 + j + 64 * m], b1[j + 64 * m], s);
            s = dpp_sum64_lane63(s);
            if (j == 63) beff[i] = s + b2[i];
        }
    } else {                              // Gx: M=4096, N=256, K=512, B=[N][K]
        const int b = bid - 72;
        const int bm = (b >> 2) * 64, bn = (b & 3) * 64;
        float acc[4][4] = {};
        gemm_tile_acc<true>(x, Wih, 512, 256, bm, bn, As, Bs, acc);
        #pragma unroll
        for (int i = 0; i < 4; ++i)
            #pragma unroll
            for (int j = 0; j < 4; ++j)
                Gx[(size_t)(bm + ty * 4 + i) * 256 + bn + tx * 4 + j] = acc[i][j];
    }
}

// ---------------------------------------------------------------------------
// scanfore: block 0 = sequential LSTM scan (1 wave); blocks 1..2048 = fore GEMM
// fore = x @ Weff^T + beff  (M=16384, N=512, K=512)
// ---------------------------------------------------------------------------
__global__ __launch_bounds__(256) void scanfore_kernel(
    const float* __restrict__ x, const float* __restrict__ Weff,
    const float* __restrict__ beff, const float* __restrict__ Gx,
    const float* __restrict__ Whh, const float* __restrict__ bih,
    const float* __restrict__ bhh, const float* __restrict__ Whr,
    float* __restrict__ c_hist, float* __restrict__ p, float* __restrict__ fore)
{
    __shared__ float As[16][68], Bs[16][68];
    if (blockIdx.x == 0) {
        if (threadIdx.x >= 64) return;
        constexpr int S = 4096;
        constexpr float L2E  = 1.4426950408889634f;
        constexpr float L2E2 = 2.8853900817779268f;
        const int j = threadIdx.x;

        const float w0n = -Whh[j]       * L2E;
        const float w1n = -Whh[64 + j]  * L2E;
        const float w2s =  Whh[128 + j] * L2E2;
        const float w3n = -Whh[192 + j] * L2E;
        const float nb0 = -(bih[j]       + bhh[j])       * L2E;
        const float nb1 = -(bih[64 + j]  + bhh[64 + j])  * L2E;
        const float b2s =  (bih[128 + j] + bhh[128 + j]) * L2E2;
        const float nb3 = -(bih[192 + j] + bhh[192 + j]) * L2E;
        const float whr = Whr[j];

        float h = 0.0f, c = 0.0f, vp = 0.0f;
        float r0[8], r1[8], r2[8], r3[8];
        #pragma unroll
        for (int s = 0; s < 8; ++s) {
            const float* Gs = Gx + (size_t)s * 256 + j;
            r0[s] = fmaf(Gs[0],  -L2E,  nb0);
            r1[s] = fmaf(Gs[64], -L2E,  nb1);
            r2[s] = fmaf(Gs[128], L2E2, b2s);
            r3[s] = fmaf(Gs[192],-L2E,  nb3);
        }

        for (int b = 0; b < S; b += 8) {
            const bool more = (b + 8) < S;
            #pragma unroll
            for (int s = 0; s < 8; ++s) {
                const int T = b + s;
                const float xi = fmaf(w0n, h, r0[s]);
                const float xf = fmaf(w1n, h, r1[s]);
                const float xg = fmaf(w2s, h, r2[s]);
                const float xo = fmaf(w3n, h, r3[s]);
                const float si = RCPF(1.0f + EXP2(xi));
                const float sf = RCPF(1.0f + EXP2(xf));
                const float tg = fmaf(-2.0f, RCPF(1.0f + EXP2(xg)), 1.0f);
                const float so = RCPF(1.0f + EXP2(xo));
                c = fmaf(sf, c, si * tg);
                c_hist[(size_t)T * 64 + j] = c;
                const float tc = fmaf(-2.0f, RCPF(1.0f + EXP2(c * L2E2)), 1.0f);
                float hv = tc * (so * whr);
                hv = dpp_sum64_lane63(hv);
                h = readlane63(hv);
                vp = (j == (T & 63)) ? h : vp;   // lane-select accumulate, no branch
                if (more) {
                    const float* Gs = Gx + (size_t)(T + 8) * 256 + j;
                    r0[s] = fmaf(Gs[0],  -L2E,  nb0);
                    r1[s] = fmaf(Gs[64], -L2E,  nb1);
                    r2[s] = fmaf(Gs[128], L2E2, b2s);
                    r3[s] = fmaf(Gs[192],-L2E,  nb3);
                }
            }
            if ((b & 63) == 56) p[b - 56 + j] = vp;  // coalesced flush, 1/64 steps
        }
    } else {
        const int bid = blockIdx.x - 1;           // 2048 tiles: 256 x 8
        const int bm = (bid >> 3) * 64, bn = (bid & 7) * 64;
        const int tx = threadIdx.x & 15, ty = threadIdx.x >> 4;
        float acc[4][4] = {};
        gemm_tile_acc<true>(x, Weff, 512, 512, bm, bn, As, Bs, acc);
        #pragma unroll
        for (int i = 0; i < 4; ++i)
            #pragma unroll
            for (int j = 0; j < 4; ++j)
                fore[(size_t)(bm + ty * 4 + i) * 512 + bn + tx * 4 + j] =
                    acc[i][j] + beff[bn + tx * 4 + j];
    }
}

// ---------------------------------------------------------------------------
// Gf = fore[0:4096] @ Wih^T   (M=4096, N=256, K=512) — 256 tiles
// ---------------------------------------------------------------------------
__global__ __launch_bounds__(256) void gf_kernel(
    const float* __restrict__ fore, const float* __restrict__ Wih,
    float* __restrict__ Gf)
{
    __shared__ float As[16][68], Bs[16][68];
    const int bid = blockIdx.x;
    const int bm = (bid >> 2) * 64, bn = (bid & 3) * 64;
    const int tx = threadIdx.x & 15, ty = threadIdx.x >> 4;
    float acc[4][4] = {};
    gemm_tile_acc<true>(fore, Wih, 512, 256, bm, bn, As, Bs, acc);
    #pragma unroll
    for (int i = 0; i < 4; ++i)
        #pragma unroll
        for (int j = 0; j < 4; ++j)
            Gf[(size_t)(bm + ty * 4 + i) * 256 + bn + tx * 4 + j] = acc[i][j];
}

// ---------------------------------------------------------------------------
// finish: blocks [0,64) forecast cells (+ forecast-output broadcast);
//         blocks [64,128) progress-output broadcast
// ---------------------------------------------------------------------------
__global__ __launch_bounds__(256) void finish_kernel(
    const float* __restrict__ Gf, const float* __restrict__ Whh,
    const float* __restrict__ bih, const float* __restrict__ bhh,
    const float* __restrict__ Whr, const float* __restrict__ c_hist,
    const float* __restrict__ p, float* __restrict__ out)
{
    constexpr int S = 4096, BS = 4 * 4096;
    const int bid = blockIdx.x;
    if (bid < 64) {
        const int w = threadIdx.x >> 6, j = threadIdx.x & 63;
        for (int o = 0; o < 16; ++o) {
            const int t = bid * 64 + w * 16 + o;
            const float h2 = p[t];
            const float c2 = c_hist[(size_t)t * 64 + j];
            const float* G = Gf + (size_t)t * 256;
            const float gi = G[j]       + bih[j]       + bhh[j]       + Whh[j] * h2;
            const float gf = G[64 + j]  + bih[64 + j]  + bhh[64 + j]  + Whh[64 + j] * h2;
            const float gg = G[128 + j] + bih[128 + j] + bhh[128 + j] + Whh[128 + j] * h2;
            const float go = G[192 + j] + bih[192 + j] + bhh[192 + j] + Whh[192 + j] * h2;
            const float cf = fsig(gf) * c2 + fsig(gi) * ftanh(gg);
            float hv = fsig(go) * ftanh(cf) * Whr[j];
            hv = dpp_sum64_lane63(hv);
            if (j == 63) {
                out[BS + 0 * S + t] = hv;
                out[BS + 1 * S + t] = hv;
                out[BS + 2 * S + t] = hv;
                out[BS + 3 * S + t] = hv;
            }
        }
    } else {
        const int i = (bid - 64) * 256 + threadIdx.x;  // 0..16383
        out[i] = p[i & (S - 1)];
    }
}

extern "C" void kernel_launch(void* const* d_in, const int* in_sizes, int n_in,
                              void* d_out, int out_size, void* d_ws, size_t ws_size,
                              hipStream_t stream) {
    const float* x   = (const float*)d_in[0];
    const float* W1  = (const float*)d_in[1];
    const float* b1  = (const float*)d_in[2];
    const float* W2  = (const float*)d_in[3];
    const float* b2  = (const float*)d_in[4];
    const float* Wih = (const float*)d_in[5];
    const float* Whh = (const float*)d_in[6];
    const float* bih = (const float*)d_in[7];
    const float* bhh = (const float*)d_in[8];
    const float* Whr = (const float*)d_in[9];
    float* out = (float*)d_out;

    constexpr int Bb = 4, S = 4096;
    const int M = Bb * S; // 16384

    float* ws     = (float*)d_ws;
    float* Weff   = ws;                       // 512*512
    float* beff   = Weff + 512 * 512;         // 512
    float* Gx     = beff + 512;               // 4096*256
    float* Gf     = Gx + S * 256;             // 4096*256
    float* c_hist = Gf + S * 256;             // 4096*64
    float* p      = c_hist + S * 64;          // 4096

    float* fore = out + 2 * M;                // (16384,512) region of d_out

    // 1) Weff/beff/Gx (all independent) in one launch
    prep_kernel<<<328, 256, 0, stream>>>(x, W1, b1, W2, b2, Wih, Weff, beff, Gx);

    // 2) scan (block 0) || fore GEMM (blocks 1..2048)
    scanfore_kernel<<<2049, 256, 0, stream>>>(
        x, Weff, beff, Gx, Whh, bih, bhh, Whr, c_hist, p, fore);

    // 3) Gf = fore @ Wih^T
    gf_kernel<<<256, 256, 0, stream>>>(fore, Wih, Gf);

    // 4) forecast cells + output broadcasts
    finish_kernel<<<128, 256, 0, stream>>>(Gf, Whh, bih, bhh, Whr, c_hist, p, out);
}

// Round 4
// 957.725 us; speedup vs baseline: 1.8410x; 1.8410x over previous
//
#include <hip/hip_runtime.h>
#include <hip/hip_bf16.h>

// B=4, S=4096, D=512, FH=2048, H=64
// outputs: progress (B*S) ++ forecast (B*S) ++ fore (B*S*D), all f32

#if __has_builtin(__builtin_amdgcn_exp2f)
__device__ __forceinline__ float EXP2(float x) { return __builtin_amdgcn_exp2f(x); }
#else
__device__ __forceinline__ float EXP2(float x) { return __expf(x * 0.6931471805599453f); }
#endif
#if __has_builtin(__builtin_amdgcn_rcpf)
__device__ __forceinline__ float RCPF(float x) { return __builtin_amdgcn_rcpf(x); }
#else
__device__ __forceinline__ float RCPF(float x) { return 1.0f / x; }
#endif

__device__ __forceinline__ float fsig(float x) { return 1.0f / (1.0f + __expf(-x)); }
__device__ __forceinline__ float ftanh(float x) { return 1.0f - 2.0f / (1.0f + __expf(2.0f * x)); }

// Wave64 sum via DPP row_shr 1/2/4/8 + row_bcast15/31; full sum lands in lane 63.
__device__ __forceinline__ float dpp_sum64_lane63(float x) {
    x += __int_as_float(__builtin_amdgcn_update_dpp(0, __float_as_int(x), 0x111, 0xf, 0xf, true));
    x += __int_as_float(__builtin_amdgcn_update_dpp(0, __float_as_int(x), 0x112, 0xf, 0xf, true));
    x += __int_as_float(__builtin_amdgcn_update_dpp(0, __float_as_int(x), 0x114, 0xf, 0xf, true));
    x += __int_as_float(__builtin_amdgcn_update_dpp(0, __float_as_int(x), 0x118, 0xf, 0xf, true));
    x += __int_as_float(__builtin_amdgcn_update_dpp(0, __float_as_int(x), 0x142, 0xf, 0xf, true));
    x += __int_as_float(__builtin_amdgcn_update_dpp(0, __float_as_int(x), 0x143, 0xf, 0xf, true));
    return x;
}
__device__ __forceinline__ float readlane63(float x) {
    return __int_as_float(__builtin_amdgcn_readlane(__float_as_int(x), 63));
}

// ---------------------------------------------------------------------------
// 64x64 f32 tile core (BK=16): fills acc[4][4] for tile (bm,bn).
//   BT=true : B is [N][K] row-major  -> C = A @ B^T
//   BT=false: B is [K][N] row-major  -> C = A @ B
// ---------------------------------------------------------------------------
template<bool BT>
__device__ void gemm_tile_acc(const float* __restrict__ A, const float* __restrict__ B,
                              int K, int N, int bm, int bn,
                              float (* __restrict__ As)[68], float (* __restrict__ Bs)[68],
                              float acc[4][4])
{
    const int tid = threadIdx.x;
    const int tx = tid & 15, ty = tid >> 4;
    for (int k0 = 0; k0 < K; k0 += 16) {
        {
            const int r = tid >> 2, cc = (tid & 3) * 4;
            const float4 av = *reinterpret_cast<const float4*>(
                &A[(size_t)(bm + r) * K + k0 + cc]);
            As[cc + 0][r] = av.x; As[cc + 1][r] = av.y;
            As[cc + 2][r] = av.z; As[cc + 3][r] = av.w;
        }
        if (BT) {
            const int r = tid >> 2, cc = (tid & 3) * 4;
            const float4 bv = *reinterpret_cast<const float4*>(
                &B[(size_t)(bn + r) * K + k0 + cc]);
            Bs[cc + 0][r] = bv.x; Bs[cc + 1][r] = bv.y;
            Bs[cc + 2][r] = bv.z; Bs[cc + 3][r] = bv.w;
        } else {
            const int r = tid >> 4, cc = (tid & 15) * 4;
            const float4 bv = *reinterpret_cast<const float4*>(
                &B[(size_t)(k0 + r) * N + bn + cc]);
            Bs[r][cc + 0] = bv.x; Bs[r][cc + 1] = bv.y;
            Bs[r][cc + 2] = bv.z; Bs[r][cc + 3] = bv.w;
        }
        __syncthreads();
        #pragma unroll
        for (int k = 0; k < 16; ++k) {
            float a[4], b[4];
            #pragma unroll
            for (int i = 0; i < 4; ++i) a[i] = As[k][ty * 4 + i];
            #pragma unroll
            for (int j = 0; j < 4; ++j) b[j] = Bs[k][tx * 4 + j];
            #pragma unroll
            for (int i = 0; i < 4; ++i)
                #pragma unroll
                for (int j = 0; j < 4; ++j)
                    acc[i][j] = fmaf(a[i], b[j], acc[i][j]);
        }
        __syncthreads();
    }
}

// ---------------------------------------------------------------------------
// prep: blocks [0,64) Weff = W2@W1 ; [64,72) beff = W2@b1+b2 ; [72,328) Gx
// ---------------------------------------------------------------------------
__global__ __launch_bounds__(256) void prep_kernel(
    const float* __restrict__ x, const float* __restrict__ W1,
    const float* __restrict__ b1, const float* __restrict__ W2,
    const float* __restrict__ b2, const float* __restrict__ Wih,
    float* __restrict__ Weff, float* __restrict__ beff, float* __restrict__ Gx)
{
    __shared__ float As[16][68], Bs[16][68];
    const int bid = blockIdx.x;
    const int tx = threadIdx.x & 15, ty = threadIdx.x >> 4;

    if (bid < 64) {                       // Weff: M=N=512, K=2048, B=[K][N]
        const int bm = (bid >> 3) * 64, bn = (bid & 7) * 64;
        float acc[4][4] = {};
        gemm_tile_acc<false>(W2, W1, 2048, 512, bm, bn, As, Bs, acc);
        #pragma unroll
        for (int i = 0; i < 4; ++i)
            #pragma unroll
            for (int j = 0; j < 4; ++j)
                Weff[(size_t)(bm + ty * 4 + i) * 512 + bn + tx * 4 + j] = acc[i][j];
    } else if (bid < 72) {                // beff
        const int w = threadIdx.x >> 6, j = threadIdx.x & 63;
        const int base = (bid - 64) * 64 + w * 16;
        for (int o = 0; o < 16; ++o) {
            const int i = base + o;
            float s = 0.0f;
            #pragma unroll
            for (int m = 0; m < 32; ++m)
                s = fmaf(W2[(size_t)i * 2048 + j + 64 * m], b1[j + 64 * m], s);
            s = dpp_sum64_lane63(s);
            if (j == 63) beff[i] = s + b2[i];
        }
    } else {                              // Gx: M=4096, N=256, K=512, B=[N][K]
        const int b = bid - 72;
        const int bm = (b >> 2) * 64, bn = (b & 3) * 64;
        float acc[4][4] = {};
        gemm_tile_acc<true>(x, Wih, 512, 256, bm, bn, As, Bs, acc);
        #pragma unroll
        for (int i = 0; i < 4; ++i)
            #pragma unroll
            for (int j = 0; j < 4; ++j)
                Gx[(size_t)(bm + ty * 4 + i) * 256 + bn + tx * 4 + j] = acc[i][j];
    }
}

// ---------------------------------------------------------------------------
// scanfore: block 0 = sequential LSTM scan (1 wave, setprio 3);
//           blocks 1..2048 = fore GEMM (fore = x @ Weff^T + beff)
// ---------------------------------------------------------------------------
__global__ __launch_bounds__(256) void scanfore_kernel(
    const float* __restrict__ x, const float* __restrict__ Weff,
    const float* __restrict__ beff, const float* __restrict__ Gx,
    const float* __restrict__ Whh, const float* __restrict__ bih,
    const float* __restrict__ bhh, const float* __restrict__ Whr,
    float* __restrict__ c_hist, float* __restrict__ p, float* __restrict__ fore)
{
    __shared__ float As[16][68], Bs[16][68];
    if (blockIdx.x == 0) {
        if (threadIdx.x >= 64) return;
        __builtin_amdgcn_s_setprio(3);   // latency-bound wave: win issue arbitration
        constexpr int S = 4096;
        constexpr float L2E  = 1.4426950408889634f;
        constexpr float L2E2 = 2.8853900817779268f;
        const int j = threadIdx.x;

        const float w0n = -Whh[j]       * L2E;
        const float w1n = -Whh[64 + j]  * L2E;
        const float w2s =  Whh[128 + j] * L2E2;
        const float w3n = -Whh[192 + j] * L2E;
        const float nb0 = -(bih[j]       + bhh[j])       * L2E;
        const float nb1 = -(bih[64 + j]  + bhh[64 + j])  * L2E;
        const float b2s =  (bih[128 + j] + bhh[128 + j]) * L2E2;
        const float nb3 = -(bih[192 + j] + bhh[192 + j]) * L2E;
        const float whr = Whr[j];

        float h = 0.0f, c = 0.0f, vp = 0.0f;
        // RAW gate ring: loads consumed 8 steps later, so the compiler can
        // defer s_waitcnt 8 steps (the round-2 latency-hiding structure).
        float g0_[8], g1_[8], g2_[8], g3_[8];
        #pragma unroll
        for (int s = 0; s < 8; ++s) {
            const float* Gs = Gx + (size_t)s * 256 + j;
            g0_[s] = Gs[0]; g1_[s] = Gs[64]; g2_[s] = Gs[128]; g3_[s] = Gs[192];
        }

        for (int b = 0; b < S; b += 8) {
            const bool more = (b + 8) < S;
            #pragma unroll
            for (int s = 0; s < 8; ++s) {
                const int T = b + s;
                // pre-activations: off the h-chain, inputs loaded 8 steps ago
                const float pre0 = fmaf(g0_[s], -L2E,  nb0);
                const float pre1 = fmaf(g1_[s], -L2E,  nb1);
                const float pre2 = fmaf(g2_[s],  L2E2, b2s);
                const float pre3 = fmaf(g3_[s], -L2E,  nb3);
                const float xi = fmaf(w0n, h, pre0);
                const float xf = fmaf(w1n, h, pre1);
                const float xg = fmaf(w2s, h, pre2);
                const float xo = fmaf(w3n, h, pre3);
                const float si = RCPF(1.0f + EXP2(xi));
                const float sf = RCPF(1.0f + EXP2(xf));
                const float tg = fmaf(-2.0f, RCPF(1.0f + EXP2(xg)), 1.0f);
                const float so = RCPF(1.0f + EXP2(xo));
                c = fmaf(sf, c, si * tg);
                c_hist[(size_t)T * 64 + j] = c;
                const float tc = fmaf(-2.0f, RCPF(1.0f + EXP2(c * L2E2)), 1.0f);
                float hv = tc * (so * whr);
                hv = dpp_sum64_lane63(hv);
                h = readlane63(hv);
                vp = (j == (T & 63)) ? h : vp;   // lane-select accumulate
                if (more) {
                    const float* Gs = Gx + (size_t)(T + 8) * 256 + j;
                    g0_[s] = Gs[0]; g1_[s] = Gs[64];
                    g2_[s] = Gs[128]; g3_[s] = Gs[192];
                }
            }
            if ((b & 63) == 56) p[b - 56 + j] = vp;  // coalesced flush, 1/64 steps
        }
    } else {
        const int bid = blockIdx.x - 1;           // 2048 tiles: 256 x 8
        const int bm = (bid >> 3) * 64, bn = (bid & 7) * 64;
        const int tx = threadIdx.x & 15, ty = threadIdx.x >> 4;
        float acc[4][4] = {};
        gemm_tile_acc<true>(x, Weff, 512, 512, bm, bn, As, Bs, acc);
        #pragma unroll
        for (int i = 0; i < 4; ++i)
            #pragma unroll
            for (int j = 0; j < 4; ++j)
                fore[(size_t)(bm + ty * 4 + i) * 512 + bn + tx * 4 + j] =
                    acc[i][j] + beff[bn + tx * 4 + j];
    }
}

// ---------------------------------------------------------------------------
// Gf = fore[0:4096] @ Wih^T   (M=4096, N=256, K=512) — 256 tiles
// ---------------------------------------------------------------------------
__global__ __launch_bounds__(256) void gf_kernel(
    const float* __restrict__ fore, const float* __restrict__ Wih,
    float* __restrict__ Gf)
{
    __shared__ float As[16][68], Bs[16][68];
    const int bid = blockIdx.x;
    const int bm = (bid >> 2) * 64, bn = (bid & 3) * 64;
    const int tx = threadIdx.x & 15, ty = threadIdx.x >> 4;
    float acc[4][4] = {};
    gemm_tile_acc<true>(fore, Wih, 512, 256, bm, bn, As, Bs, acc);
    #pragma unroll
    for (int i = 0; i < 4; ++i)
        #pragma unroll
        for (int j = 0; j < 4; ++j)
            Gf[(size_t)(bm + ty * 4 + i) * 256 + bn + tx * 4 + j] = acc[i][j];
}

// ---------------------------------------------------------------------------
// finish: blocks [0,64) forecast cells (+ forecast broadcast);
//         blocks [64,128) progress broadcast
// ---------------------------------------------------------------------------
__global__ __launch_bounds__(256) void finish_kernel(
    const float* __restrict__ Gf, const float* __restrict__ Whh,
    const float* __restrict__ bih, const float* __restrict__ bhh,
    const float* __restrict__ Whr, const float* __restrict__ c_hist,
    const float* __restrict__ p, float* __restrict__ out)
{
    constexpr int S = 4096, BS = 4 * 4096;
    const int bid = blockIdx.x;
    if (bid < 64) {
        const int w = threadIdx.x >> 6, j = threadIdx.x & 63;
        for (int o = 0; o < 16; ++o) {
            const int t = bid * 64 + w * 16 + o;
            const float h2 = p[t];
            const float c2 = c_hist[(size_t)t * 64 + j];
            const float* G = Gf + (size_t)t * 256;
            const float gi = G[j]       + bih[j]       + bhh[j]       + Whh[j] * h2;
            const float gf = G[64 + j]  + bih[64 + j]  + bhh[64 + j]  + Whh[64 + j] * h2;
            const float gg = G[128 + j] + bih[128 + j] + bhh[128 + j] + Whh[128 + j] * h2;
            const float go = G[192 + j] + bih[192 + j] + bhh[192 + j] + Whh[192 + j] * h2;
            const float cf = fsig(gf) * c2 + fsig(gi) * ftanh(gg);
            float hv = fsig(go) * ftanh(cf) * Whr[j];
            hv = dpp_sum64_lane63(hv);
            if (j == 63) {
                out[BS + 0 * S + t] = hv;
                out[BS + 1 * S + t] = hv;
                out[BS + 2 * S + t] = hv;
                out[BS + 3 * S + t] = hv;
            }
        }
    } else {
        const int i = (bid - 64) * 256 + threadIdx.x;  // 0..16383
        out[i] = p[i & (S - 1)];
    }
}

extern "C" void kernel_launch(void* const* d_in, const int* in_sizes, int n_in,
                              void* d_out, int out_size, void* d_ws, size_t ws_size,
                              hipStream_t stream) {
    const float* x   = (const float*)d_in[0];
    const float* W1  = (const float*)d_in[1];
    const float* b1  = (const float*)d_in[2];
    const float* W2  = (const float*)d_in[3];
    const float* b2  = (const float*)d_in[4];
    const float* Wih = (const float*)d_in[5];
    const float* Whh = (const float*)d_in[6];
    const float* bih = (const float*)d_in[7];
    const float* bhh = (const float*)d_in[8];
    const float* Whr = (const float*)d_in[9];
    float* out = (float*)d_out;

    constexpr int Bb = 4, S = 4096;
    const int M = Bb * S; // 16384

    float* ws     = (float*)d_ws;
    float* Weff   = ws;                       // 512*512
    float* beff   = Weff + 512 * 512;         // 512
    float* Gx     = beff + 512;               // 4096*256
    float* Gf     = Gx + S * 256;             // 4096*256
    float* c_hist = Gf + S * 256;             // 4096*64
    float* p      = c_hist + S * 64;          // 4096

    float* fore = out + 2 * M;                // (16384,512) region of d_out

    // 1) Weff/beff/Gx (all independent) in one launch
    prep_kernel<<<328, 256, 0, stream>>>(x, W1, b1, W2, b2, Wih, Weff, beff, Gx);

    // 2) scan (block 0, high prio) || fore GEMM (blocks 1..2048)
    scanfore_kernel<<<2049, 256, 0, stream>>>(
        x, Weff, beff, Gx, Whh, bih, bhh, Whr, c_hist, p, fore);

    // 3) Gf = fore @ Wih^T
    gf_kernel<<<256, 256, 0, stream>>>(fore, Wih, Gf);

    // 4) forecast cells + output broadcasts
    finish_kernel<<<128, 256, 0, stream>>>(Gf, Whh, bih, bhh, Whr, c_hist, p, out);
}

// Round 5
// 888.484 us; speedup vs baseline: 1.9845x; 1.0779x over previous
//
#include <hip/hip_runtime.h>
#include <hip/hip_bf16.h>

// B=4, S=4096, D=512, FH=2048, H=64
// outputs: progress (B*S) ++ forecast (B*S) ++ fore (B*S*D), all f32

#if __has_builtin(__builtin_amdgcn_exp2f)
__device__ __forceinline__ float EXP2(float x) { return __builtin_amdgcn_exp2f(x); }
#else
__device__ __forceinline__ float EXP2(float x) { return __expf(x * 0.6931471805599453f); }
#endif
#if __has_builtin(__builtin_amdgcn_rcpf)
__device__ __forceinline__ float RCPF(float x) { return __builtin_amdgcn_rcpf(x); }
#else
__device__ __forceinline__ float RCPF(float x) { return 1.0f / x; }
#endif

__device__ __forceinline__ float fsig(float x) { return 1.0f / (1.0f + __expf(-x)); }
__device__ __forceinline__ float ftanh(float x) { return 1.0f - 2.0f / (1.0f + __expf(2.0f * x)); }

// Wave64 sum via DPP row_shr 1/2/4/8 + row_bcast15/31; full sum lands in lane 63.
__device__ __forceinline__ float dpp_sum64_lane63(float x) {
    x += __int_as_float(__builtin_amdgcn_update_dpp(0, __float_as_int(x), 0x111, 0xf, 0xf, true));
    x += __int_as_float(__builtin_amdgcn_update_dpp(0, __float_as_int(x), 0x112, 0xf, 0xf, true));
    x += __int_as_float(__builtin_amdgcn_update_dpp(0, __float_as_int(x), 0x114, 0xf, 0xf, true));
    x += __int_as_float(__builtin_amdgcn_update_dpp(0, __float_as_int(x), 0x118, 0xf, 0xf, true));
    x += __int_as_float(__builtin_amdgcn_update_dpp(0, __float_as_int(x), 0x142, 0xf, 0xf, true));
    x += __int_as_float(__builtin_amdgcn_update_dpp(0, __float_as_int(x), 0x143, 0xf, 0xf, true));
    return x;
}
__device__ __forceinline__ float readlane63(float x) {
    return __int_as_float(__builtin_amdgcn_readlane(__float_as_int(x), 63));
}

// ---------------------------------------------------------------------------
// 64x64 f32 tile core (BK=16): fills acc[4][4] for tile (bm,bn).
//   BT=true : B is [N][K] row-major  -> C = A @ B^T
//   BT=false: B is [K][N] row-major  -> C = A @ B
// ---------------------------------------------------------------------------
template<bool BT>
__device__ void gemm_tile_acc(const float* __restrict__ A, const float* __restrict__ B,
                              int K, int N, int bm, int bn,
                              float (* __restrict__ As)[68], float (* __restrict__ Bs)[68],
                              float acc[4][4])
{
    const int tid = threadIdx.x;
    const int tx = tid & 15, ty = tid >> 4;
    for (int k0 = 0; k0 < K; k0 += 16) {
        {
            const int r = tid >> 2, cc = (tid & 3) * 4;
            const float4 av = *reinterpret_cast<const float4*>(
                &A[(size_t)(bm + r) * K + k0 + cc]);
            As[cc + 0][r] = av.x; As[cc + 1][r] = av.y;
            As[cc + 2][r] = av.z; As[cc + 3][r] = av.w;
        }
        if (BT) {
            const int r = tid >> 2, cc = (tid & 3) * 4;
            const float4 bv = *reinterpret_cast<const float4*>(
                &B[(size_t)(bn + r) * K + k0 + cc]);
            Bs[cc + 0][r] = bv.x; Bs[cc + 1][r] = bv.y;
            Bs[cc + 2][r] = bv.z; Bs[cc + 3][r] = bv.w;
        } else {
            const int r = tid >> 4, cc = (tid & 15) * 4;
            const float4 bv = *reinterpret_cast<const float4*>(
                &B[(size_t)(k0 + r) * N + bn + cc]);
            Bs[r][cc + 0] = bv.x; Bs[r][cc + 1] = bv.y;
            Bs[r][cc + 2] = bv.z; Bs[r][cc + 3] = bv.w;
        }
        __syncthreads();
        #pragma unroll
        for (int k = 0; k < 16; ++k) {
            float a[4], b[4];
            #pragma unroll
            for (int i = 0; i < 4; ++i) a[i] = As[k][ty * 4 + i];
            #pragma unroll
            for (int j = 0; j < 4; ++j) b[j] = Bs[k][tx * 4 + j];
            #pragma unroll
            for (int i = 0; i < 4; ++i)
                #pragma unroll
                for (int j = 0; j < 4; ++j)
                    acc[i][j] = fmaf(a[i], b[j], acc[i][j]);
        }
        __syncthreads();
    }
}

// ---------------------------------------------------------------------------
// prep: blocks [0,64) Weff = W2@W1 ; [64,72) beff = W2@b1+b2 ; [72,328) Gx
// ---------------------------------------------------------------------------
__global__ __launch_bounds__(256) void prep_kernel(
    const float* __restrict__ x, const float* __restrict__ W1,
    const float* __restrict__ b1, const float* __restrict__ W2,
    const float* __restrict__ b2, const float* __restrict__ Wih,
    float* __restrict__ Weff, float* __restrict__ beff, float* __restrict__ Gx)
{
    __shared__ float As[16][68], Bs[16][68];
    const int bid = blockIdx.x;
    const int tx = threadIdx.x & 15, ty = threadIdx.x >> 4;

    if (bid < 64) {                       // Weff: M=N=512, K=2048, B=[K][N]
        const int bm = (bid >> 3) * 64, bn = (bid & 7) * 64;
        float acc[4][4] = {};
        gemm_tile_acc<false>(W2, W1, 2048, 512, bm, bn, As, Bs, acc);
        #pragma unroll
        for (int i = 0; i < 4; ++i)
            #pragma unroll
            for (int j = 0; j < 4; ++j)
                Weff[(size_t)(bm + ty * 4 + i) * 512 + bn + tx * 4 + j] = acc[i][j];
    } else if (bid < 72) {                // beff
        const int w = threadIdx.x >> 6, j = threadIdx.x & 63;
        const int base = (bid - 64) * 64 + w * 16;
        for (int o = 0; o < 16; ++o) {
            const int i = base + o;
            float s = 0.0f;
            #pragma unroll
            for (int m = 0; m < 32; ++m)
                s = fmaf(W2[(size_t)i * 2048 + j + 64 * m], b1[j + 64 * m], s);
            s = dpp_sum64_lane63(s);
            if (j == 63) beff[i] = s + b2[i];
        }
    } else {                              // Gx: M=4096, N=256, K=512, B=[N][K]
        const int b = bid - 72;
        const int bm = (b >> 2) * 64, bn = (b & 3) * 64;
        float acc[4][4] = {};
        gemm_tile_acc<true>(x, Wih, 512, 256, bm, bn, As, Bs, acc);
        #pragma unroll
        for (int i = 0; i < 4; ++i)
            #pragma unroll
            for (int j = 0; j < 4; ++j)
                Gx[(size_t)(bm + ty * 4 + i) * 256 + bn + tx * 4 + j] = acc[i][j];
    }
}

// ---------------------------------------------------------------------------
// wg: blocks [0,32) Wg = Wih @ Weff (256x512, K=512); block 32: bf2 = Wih @ beff
// ---------------------------------------------------------------------------
__global__ __launch_bounds__(256) void wg_kernel(
    const float* __restrict__ Wih, const float* __restrict__ Weff,
    const float* __restrict__ beff, float* __restrict__ Wg, float* __restrict__ bf2)
{
    __shared__ float As[16][68], Bs[16][68];
    const int bid = blockIdx.x;
    if (bid < 32) {                        // M=256 (4 tiles), N=512 (8 tiles)
        const int bm = (bid >> 3) * 64, bn = (bid & 7) * 64;
        const int tx = threadIdx.x & 15, ty = threadIdx.x >> 4;
        float acc[4][4] = {};
        gemm_tile_acc<false>(Wih, Weff, 512, 512, bm, bn, As, Bs, acc);
        #pragma unroll
        for (int i = 0; i < 4; ++i)
            #pragma unroll
            for (int j = 0; j < 4; ++j)
                Wg[(size_t)(bm + ty * 4 + i) * 512 + bn + tx * 4 + j] = acc[i][j];
    } else {                               // bf2: 4 waves x 64 outputs
        const int w = threadIdx.x >> 6, j = threadIdx.x & 63;
        for (int o = 0; o < 64; ++o) {
            const int i = w * 64 + o;
            float s = 0.0f;
            #pragma unroll
            for (int m = 0; m < 8; ++m)
                s = fmaf(Wih[(size_t)i * 512 + j + 64 * m], beff[j + 64 * m], s);
            s = dpp_sum64_lane63(s);
            if (j == 63) bf2[i] = s;
        }
    }
}

// ---------------------------------------------------------------------------
// scanfore: block 0 = LDS-staged sequential scan (wave0 scans, waves1-3 load);
//           blocks [1,2049) fore = x @ Weff^T + beff  (2048 tiles);
//           blocks [2049,2305) Gf = x[0:4096] @ Wg^T  (256 tiles)
// ---------------------------------------------------------------------------
__global__ __launch_bounds__(256) void scanfore_kernel(
    const float* __restrict__ x, const float* __restrict__ Weff,
    const float* __restrict__ beff, const float* __restrict__ Gx,
    const float* __restrict__ Wg,
    const float* __restrict__ Whh, const float* __restrict__ bih,
    const float* __restrict__ bhh, const float* __restrict__ Whr,
    float* __restrict__ c_hist, float* __restrict__ p,
    float* __restrict__ fore, float* __restrict__ Gf)
{
    __shared__ float As[16][68], Bs[16][68];
    __shared__ __align__(16) float gbuf[2][32 * 256];   // 64KB double buffer
    constexpr int S = 4096, CH = 32, NCH = S / CH;      // 128 chunks

    if (blockIdx.x == 0) {
        const int tid = threadIdx.x;
        // all 256 threads: load chunk 0 (steps 0..31 = 2048 float4)
        {
            const float4* src = reinterpret_cast<const float4*>(Gx);
            float4* dst = reinterpret_cast<float4*>(gbuf[0]);
            #pragma unroll
            for (int u = 0; u < 8; ++u) dst[tid + u * 256] = src[tid + u * 256];
        }
        __syncthreads();

        if (tid >= 64) {
            // ---- loader waves: stream chunk cc+1 into gbuf[(cc+1)&1] ----
            const int lt = tid - 64;  // 0..191
            for (int cc = 0; cc < NCH; ++cc) {
                if (cc + 1 < NCH) {
                    const float4* src = reinterpret_cast<const float4*>(
                        Gx + (size_t)(cc + 1) * CH * 256);
                    float4* dst = reinterpret_cast<float4*>(gbuf[(cc + 1) & 1]);
                    float4 tmp[11];
                    #pragma unroll
                    for (int u = 0; u < 11; ++u) {
                        const int idx = lt + u * 192;
                        if (idx < 2048) tmp[u] = src[idx];
                    }
                    #pragma unroll
                    for (int u = 0; u < 11; ++u) {
                        const int idx = lt + u * 192;
                        if (idx < 2048) dst[idx] = tmp[u];
                    }
                }
                __syncthreads();
            }
            return;
        }

        // ---- wave 0: the sequential scan ----
        __builtin_amdgcn_s_setprio(3);
        constexpr float L2E  = 1.4426950408889634f;
        constexpr float L2E2 = 2.8853900817779268f;
        const int j = tid;

        const float w0n = -Whh[j]       * L2E;
        const float w1n = -Whh[64 + j]  * L2E;
        const float w2s =  Whh[128 + j] * L2E2;
        const float w3n = -Whh[192 + j] * L2E;
        const float nb0 = -(bih[j]       + bhh[j])       * L2E;
        const float nb1 = -(bih[64 + j]  + bhh[64 + j])  * L2E;
        const float b2s =  (bih[128 + j] + bhh[128 + j]) * L2E2;
        const float nb3 = -(bih[192 + j] + bhh[192 + j]) * L2E;
        const float whr = Whr[j];

        float h = 0.0f, c = 0.0f, vp = 0.0f;

        for (int cc = 0; cc < NCH; ++cc) {
            const float* buf = gbuf[cc & 1];
            float r0[4], r1[4], r2[4], r3[4];
            #pragma unroll
            for (int si = 0; si < 4; ++si) {
                const float* Bp = buf + si * 256 + j;
                r0[si] = Bp[0]; r1[si] = Bp[64]; r2[si] = Bp[128]; r3[si] = Bp[192];
            }
            for (int s8 = 0; s8 < CH; s8 += 4) {
                #pragma unroll
                for (int si = 0; si < 4; ++si) {
                    const int s = s8 + si;
                    const int T = cc * CH + s;
                    const float pre0 = fmaf(r0[si], -L2E,  nb0);
                    const float pre1 = fmaf(r1[si], -L2E,  nb1);
                    const float pre2 = fmaf(r2[si],  L2E2, b2s);
                    const float pre3 = fmaf(r3[si], -L2E,  nb3);
                    const float xi = fmaf(w0n, h, pre0);
                    const float xf = fmaf(w1n, h, pre1);
                    const float xg = fmaf(w2s, h, pre2);
                    const float xo = fmaf(w3n, h, pre3);
                    const float si_ = RCPF(1.0f + EXP2(xi));
                    const float sf  = RCPF(1.0f + EXP2(xf));
                    const float tg  = fmaf(-2.0f, RCPF(1.0f + EXP2(xg)), 1.0f);
                    const float so  = RCPF(1.0f + EXP2(xo));
                    c = fmaf(sf, c, si_ * tg);
                    c_hist[(size_t)T * 64 + j] = c;
                    const float tc = fmaf(-2.0f, RCPF(1.0f + EXP2(c * L2E2)), 1.0f);
                    float hv = tc * (so * whr);
                    hv = dpp_sum64_lane63(hv);
                    h = readlane63(hv);
                    vp = (j == (T & 63)) ? h : vp;
                    if (s + 4 < CH) {
                        const float* Bp = buf + (s + 4) * 256 + j;
                        r0[si] = Bp[0]; r1[si] = Bp[64];
                        r2[si] = Bp[128]; r3[si] = Bp[192];
                    }
                }
            }
            if (cc & 1) p[(cc - 1) * CH + j] = vp;  // coalesced, every 64 steps
            __syncthreads();
        }
        return;
    }

    const int bid = blockIdx.x - 1;
    const int tx = threadIdx.x & 15, ty = threadIdx.x >> 4;
    if (bid < 2048) {                      // fore tiles: 256 x 8
        const int bm = (bid >> 3) * 64, bn = (bid & 7) * 64;
        float acc[4][4] = {};
        gemm_tile_acc<true>(x, Weff, 512, 512, bm, bn, As, Bs, acc);
        #pragma unroll
        for (int i = 0; i < 4; ++i)
            #pragma unroll
            for (int j = 0; j < 4; ++j)
                fore[(size_t)(bm + ty * 4 + i) * 512 + bn + tx * 4 + j] =
                    acc[i][j] + beff[bn + tx * 4 + j];
    } else {                               // Gf tiles: 64 x 4
        const int t = bid - 2048;
        const int bm = (t >> 2) * 64, bn = (t & 3) * 64;
        float acc[4][4] = {};
        gemm_tile_acc<true>(x, Wg, 512, 256, bm, bn, As, Bs, acc);
        #pragma unroll
        for (int i = 0; i < 4; ++i)
            #pragma unroll
            for (int j = 0; j < 4; ++j)
                Gf[(size_t)(bm + ty * 4 + i) * 256 + bn + tx * 4 + j] = acc[i][j];
    }
}

// ---------------------------------------------------------------------------
// finish: blocks [0,64) forecast cells (+ forecast broadcast; gates need +bf2);
//         blocks [64,128) progress broadcast
// ---------------------------------------------------------------------------
__global__ __launch_bounds__(256) void finish_kernel(
    const float* __restrict__ Gf, const float* __restrict__ bf2,
    const float* __restrict__ Whh, const float* __restrict__ bih,
    const float* __restrict__ bhh, const float* __restrict__ Whr,
    const float* __restrict__ c_hist, const float* __restrict__ p,
    float* __restrict__ out)
{
    constexpr int S = 4096, BS = 4 * 4096;
    const int bid = blockIdx.x;
    if (bid < 64) {
        const int w = threadIdx.x >> 6, j = threadIdx.x & 63;
        const float bi0 = bf2[j]       + bih[j]       + bhh[j];
        const float bi1 = bf2[64 + j]  + bih[64 + j]  + bhh[64 + j];
        const float bi2 = bf2[128 + j] + bih[128 + j] + bhh[128 + j];
        const float bi3 = bf2[192 + j] + bih[192 + j] + bhh[192 + j];
        for (int o = 0; o < 16; ++o) {
            const int t = bid * 64 + w * 16 + o;
            const float h2 = p[t];
            const float c2 = c_hist[(size_t)t * 64 + j];
            const float* G = Gf + (size_t)t * 256;
            const float gi = G[j]       + bi0 + Whh[j] * h2;
            const float gf = G[64 + j]  + bi1 + Whh[64 + j] * h2;
            const float gg = G[128 + j] + bi2 + Whh[128 + j] * h2;
            const float go = G[192 + j] + bi3 + Whh[192 + j] * h2;
            const float cf = fsig(gf) * c2 + fsig(gi) * ftanh(gg);
            float hv = fsig(go) * ftanh(cf) * Whr[j];
            hv = dpp_sum64_lane63(hv);
            if (j == 63) {
                out[BS + 0 * S + t] = hv;
                out[BS + 1 * S + t] = hv;
                out[BS + 2 * S + t] = hv;
                out[BS + 3 * S + t] = hv;
            }
        }
    } else {
        const int i = (bid - 64) * 256 + threadIdx.x;  // 0..16383
        out[i] = p[i & (S - 1)];
    }
}

extern "C" void kernel_launch(void* const* d_in, const int* in_sizes, int n_in,
                              void* d_out, int out_size, void* d_ws, size_t ws_size,
                              hipStream_t stream) {
    const float* x   = (const float*)d_in[0];
    const float* W1  = (const float*)d_in[1];
    const float* b1  = (const float*)d_in[2];
    const float* W2  = (const float*)d_in[3];
    const float* b2  = (const float*)d_in[4];
    const float* Wih = (const float*)d_in[5];
    const float* Whh = (const float*)d_in[6];
    const float* bih = (const float*)d_in[7];
    const float* bhh = (const float*)d_in[8];
    const float* Whr = (const float*)d_in[9];
    float* out = (float*)d_out;

    constexpr int Bb = 4, S = 4096;
    const int M = Bb * S; // 16384

    float* ws     = (float*)d_ws;
    float* Weff   = ws;                       // 512*512
    float* beff   = Weff + 512 * 512;         // 512
    float* Gx     = beff + 512;               // 4096*256
    float* Gf     = Gx + S * 256;             // 4096*256
    float* c_hist = Gf + S * 256;             // 4096*64
    float* p      = c_hist + S * 64;          // 4096
    float* Wg     = p + S;                    // 256*512
    float* bf2    = Wg + 256 * 512;           // 256

    float* fore = out + 2 * M;                // (16384,512) region of d_out

    // 1) Weff/beff/Gx (all independent)
    prep_kernel<<<328, 256, 0, stream>>>(x, W1, b1, W2, b2, Wih, Weff, beff, Gx);

    // 2) Wg = Wih@Weff, bf2 = Wih@beff  (enables Gf without waiting on fore)
    wg_kernel<<<33, 256, 0, stream>>>(Wih, Weff, beff, Wg, bf2);

    // 3) scan (block 0, LDS-staged) || fore GEMM || Gf GEMM
    scanfore_kernel<<<2305, 256, 0, stream>>>(
        x, Weff, beff, Gx, Wg, Whh, bih, bhh, Whr, c_hist, p, fore, Gf);

    // 4) forecast cells + output broadcasts
    finish_kernel<<<128, 256, 0, stream>>>(
        Gf, bf2, Whh, bih, bhh, Whr, c_hist, p, out);
}

// Round 6
// 703.602 us; speedup vs baseline: 2.5060x; 1.2628x over previous
//
#include <hip/hip_runtime.h>
#include <hip/hip_bf16.h>

// B=4, S=4096, D=512, FH=2048, H=64
// outputs: progress (B*S) ++ forecast (B*S) ++ fore (B*S*D), all f32

#if __has_builtin(__builtin_amdgcn_exp2f)
__device__ __forceinline__ float EXP2(float x) { return __builtin_amdgcn_exp2f(x); }
#else
__device__ __forceinline__ float EXP2(float x) { return __expf(x * 0.6931471805599453f); }
#endif
#if __has_builtin(__builtin_amdgcn_rcpf)
__device__ __forceinline__ float RCPF(float x) { return __builtin_amdgcn_rcpf(x); }
#else
__device__ __forceinline__ float RCPF(float x) { return 1.0f / x; }
#endif

__device__ __forceinline__ float fsig(float x) { return 1.0f / (1.0f + __expf(-x)); }
__device__ __forceinline__ float ftanh(float x) { return 1.0f - 2.0f / (1.0f + __expf(2.0f * x)); }

// Wave64 sum via DPP row_shr 1/2/4/8 + row_bcast15/31; full sum lands in lane 63.
__device__ __forceinline__ float dpp_sum64_lane63(float x) {
    x += __int_as_float(__builtin_amdgcn_update_dpp(0, __float_as_int(x), 0x111, 0xf, 0xf, true));
    x += __int_as_float(__builtin_amdgcn_update_dpp(0, __float_as_int(x), 0x112, 0xf, 0xf, true));
    x += __int_as_float(__builtin_amdgcn_update_dpp(0, __float_as_int(x), 0x114, 0xf, 0xf, true));
    x += __int_as_float(__builtin_amdgcn_update_dpp(0, __float_as_int(x), 0x118, 0xf, 0xf, true));
    x += __int_as_float(__builtin_amdgcn_update_dpp(0, __float_as_int(x), 0x142, 0xf, 0xf, true));
    x += __int_as_float(__builtin_amdgcn_update_dpp(0, __float_as_int(x), 0x143, 0xf, 0xf, true));
    return x;
}
__device__ __forceinline__ float readlane63(float x) {
    return __int_as_float(__builtin_amdgcn_readlane(__float_as_int(x), 63));
}

// ---------------------------------------------------------------------------
// 64x64 f32 tile core (BK=16): fills acc[4][4] for tile (bm,bn).
//   BT=true : B is [N][K] row-major  -> C = A @ B^T
//   BT=false: B is [K][N] row-major  -> C = A @ B
// ---------------------------------------------------------------------------
template<bool BT>
__device__ void gemm_tile_acc(const float* __restrict__ A, const float* __restrict__ B,
                              int K, int N, int bm, int bn,
                              float (* __restrict__ As)[68], float (* __restrict__ Bs)[68],
                              float acc[4][4])
{
    const int tid = threadIdx.x;
    const int tx = tid & 15, ty = tid >> 4;
    for (int k0 = 0; k0 < K; k0 += 16) {
        {
            const int r = tid >> 2, cc = (tid & 3) * 4;
            const float4 av = *reinterpret_cast<const float4*>(
                &A[(size_t)(bm + r) * K + k0 + cc]);
            As[cc + 0][r] = av.x; As[cc + 1][r] = av.y;
            As[cc + 2][r] = av.z; As[cc + 3][r] = av.w;
        }
        if (BT) {
            const int r = tid >> 2, cc = (tid & 3) * 4;
            const float4 bv = *reinterpret_cast<const float4*>(
                &B[(size_t)(bn + r) * K + k0 + cc]);
            Bs[cc + 0][r] = bv.x; Bs[cc + 1][r] = bv.y;
            Bs[cc + 2][r] = bv.z; Bs[cc + 3][r] = bv.w;
        } else {
            const int r = tid >> 4, cc = (tid & 15) * 4;
            const float4 bv = *reinterpret_cast<const float4*>(
                &B[(size_t)(k0 + r) * N + bn + cc]);
            Bs[r][cc + 0] = bv.x; Bs[r][cc + 1] = bv.y;
            Bs[r][cc + 2] = bv.z; Bs[r][cc + 3] = bv.w;
        }
        __syncthreads();
        #pragma unroll
        for (int k = 0; k < 16; ++k) {
            float a[4], b[4];
            #pragma unroll
            for (int i = 0; i < 4; ++i) a[i] = As[k][ty * 4 + i];
            #pragma unroll
            for (int j = 0; j < 4; ++j) b[j] = Bs[k][tx * 4 + j];
            #pragma unroll
            for (int i = 0; i < 4; ++i)
                #pragma unroll
                for (int j = 0; j < 4; ++j)
                    acc[i][j] = fmaf(a[i], b[j], acc[i][j]);
        }
        __syncthreads();
    }
}

// ---------------------------------------------------------------------------
// prep: blocks [0,64) Weff = W2@W1 ; [64,72) beff = W2@b1+b2 ; [72,328) Gx
// ---------------------------------------------------------------------------
__global__ __launch_bounds__(256) void prep_kernel(
    const float* __restrict__ x, const float* __restrict__ W1,
    const float* __restrict__ b1, const float* __restrict__ W2,
    const float* __restrict__ b2, const float* __restrict__ Wih,
    float* __restrict__ Weff, float* __restrict__ beff, float* __restrict__ Gx)
{
    __shared__ float As[16][68], Bs[16][68];
    const int bid = blockIdx.x;
    const int tx = threadIdx.x & 15, ty = threadIdx.x >> 4;

    if (bid < 64) {                       // Weff: M=N=512, K=2048, B=[K][N]
        const int bm = (bid >> 3) * 64, bn = (bid & 7) * 64;
        float acc[4][4] = {};
        gemm_tile_acc<false>(W2, W1, 2048, 512, bm, bn, As, Bs, acc);
        #pragma unroll
        for (int i = 0; i < 4; ++i)
            #pragma unroll
            for (int j = 0; j < 4; ++j)
                Weff[(size_t)(bm + ty * 4 + i) * 512 + bn + tx * 4 + j] = acc[i][j];
    } else if (bid < 72) {                // beff
        const int w = threadIdx.x >> 6, j = threadIdx.x & 63;
        const int base = (bid - 64) * 64 + w * 16;
        for (int o = 0; o < 16; ++o) {
            const int i = base + o;
            float s = 0.0f;
            #pragma unroll
            for (int m = 0; m < 32; ++m)
                s = fmaf(W2[(size_t)i * 2048 + j + 64 * m], b1[j + 64 * m], s);
            s = dpp_sum64_lane63(s);
            if (j == 63) beff[i] = s + b2[i];
        }
    } else {                              // Gx: M=4096, N=256, K=512, B=[N][K]
        const int b = bid - 72;
        const int bm = (b >> 2) * 64, bn = (b & 3) * 64;
        float acc[4][4] = {};
        gemm_tile_acc<true>(x, Wih, 512, 256, bm, bn, As, Bs, acc);
        #pragma unroll
        for (int i = 0; i < 4; ++i)
            #pragma unroll
            for (int j = 0; j < 4; ++j)
                Gx[(size_t)(bm + ty * 4 + i) * 256 + bn + tx * 4 + j] = acc[i][j];
    }
}

// ---------------------------------------------------------------------------
// wg: blocks [0,32) Wg = Wih @ Weff (256x512, K=512); block 32: bf2 = Wih @ beff
// ---------------------------------------------------------------------------
__global__ __launch_bounds__(256) void wg_kernel(
    const float* __restrict__ Wih, const float* __restrict__ Weff,
    const float* __restrict__ beff, float* __restrict__ Wg, float* __restrict__ bf2)
{
    __shared__ float As[16][68], Bs[16][68];
    const int bid = blockIdx.x;
    if (bid < 32) {                        // M=256 (4 tiles), N=512 (8 tiles)
        const int bm = (bid >> 3) * 64, bn = (bid & 7) * 64;
        const int tx = threadIdx.x & 15, ty = threadIdx.x >> 4;
        float acc[4][4] = {};
        gemm_tile_acc<false>(Wih, Weff, 512, 512, bm, bn, As, Bs, acc);
        #pragma unroll
        for (int i = 0; i < 4; ++i)
            #pragma unroll
            for (int j = 0; j < 4; ++j)
                Wg[(size_t)(bm + ty * 4 + i) * 512 + bn + tx * 4 + j] = acc[i][j];
    } else {                               // bf2: 4 waves x 64 outputs
        const int w = threadIdx.x >> 6, j = threadIdx.x & 63;
        for (int o = 0; o < 64; ++o) {
            const int i = w * 64 + o;
            float s = 0.0f;
            #pragma unroll
            for (int m = 0; m < 8; ++m)
                s = fmaf(Wih[(size_t)i * 512 + j + 64 * m], beff[j + 64 * m], s);
            s = dpp_sum64_lane63(s);
            if (j == 63) bf2[i] = s;
        }
    }
}

// ---------------------------------------------------------------------------
// scanfore: block 0 = LDS-staged sequential scan (wave0 scans with depth-8
//           register ring; waves1-3 stream Gx in and flush c out);
//           blocks [1,2049) fore = x @ Weff^T + beff  (2048 tiles);
//           blocks [2049,2305) Gf = x[0:4096] @ Wg^T  (256 tiles)
// ---------------------------------------------------------------------------
__global__ __launch_bounds__(256) void scanfore_kernel(
    const float* __restrict__ x, const float* __restrict__ Weff,
    const float* __restrict__ beff, const float* __restrict__ Gx,
    const float* __restrict__ Wg,
    const float* __restrict__ Whh, const float* __restrict__ bih,
    const float* __restrict__ bhh, const float* __restrict__ Whr,
    float* __restrict__ c_hist, float* __restrict__ p,
    float* __restrict__ fore, float* __restrict__ Gf)
{
    // LDS layout (floats): gbuf0[8192] | gbuf1[8192] | cbuf0[2048] | cbuf1[2048]
    // = 20480 floats = 80 KB. GEMM blocks alias As/Bs at the front (8.5 KB).
    __shared__ __align__(16) float smem[20480];
    constexpr int S = 4096, CH = 32, NCH = S / CH;      // 128 chunks

    if (blockIdx.x == 0) {
        const int tid = threadIdx.x;
        float* gbuf0 = smem;
        float* gbuf1 = smem + 8192;
        float* cbuf0 = smem + 16384;
        float* cbuf1 = smem + 18432;

        // all 256 threads: load chunk 0 (2048 float4)
        {
            const float4* src = reinterpret_cast<const float4*>(Gx);
            float4* dst = reinterpret_cast<float4*>(gbuf0);
            #pragma unroll
            for (int u = 0; u < 8; ++u) dst[tid + u * 256] = src[tid + u * 256];
        }
        __syncthreads();

        if (tid >= 64) {
            // ---- loader waves: stream gbuf in, flush cbuf out ----
            const int lt = tid - 64;  // 0..191
            for (int cc = 0; cc < NCH; ++cc) {
                if (cc + 1 < NCH) {
                    const float4* src = reinterpret_cast<const float4*>(
                        Gx + (size_t)(cc + 1) * CH * 256);
                    float4* dst = reinterpret_cast<float4*>((cc + 1) & 1 ? gbuf1 : gbuf0);
                    float4 tmp[11];
                    #pragma unroll
                    for (int u = 0; u < 11; ++u) {
                        const int idx = lt + u * 192;
                        if (idx < 2048) tmp[u] = src[idx];
                    }
                    #pragma unroll
                    for (int u = 0; u < 11; ++u) {
                        const int idx = lt + u * 192;
                        if (idx < 2048) dst[idx] = tmp[u];
                    }
                }
                if (cc >= 1) {           // flush c of chunk cc-1
                    const float4* csrc = reinterpret_cast<const float4*>(
                        (cc - 1) & 1 ? cbuf1 : cbuf0);
                    float4* cdst = reinterpret_cast<float4*>(
                        c_hist + (size_t)(cc - 1) * CH * 64);
                    #pragma unroll
                    for (int u = 0; u < 3; ++u) {
                        const int idx = lt + u * 192;
                        if (idx < 512) cdst[idx] = csrc[idx];
                    }
                }
                __syncthreads();
            }
            // flush final chunk's c
            {
                const float4* csrc = reinterpret_cast<const float4*>(
                    (NCH - 1) & 1 ? cbuf1 : cbuf0);
                float4* cdst = reinterpret_cast<float4*>(
                    c_hist + (size_t)(NCH - 1) * CH * 64);
                #pragma unroll
                for (int u = 0; u < 3; ++u) {
                    const int idx = lt + u * 192;
                    if (idx < 512) cdst[idx] = csrc[idx];
                }
            }
            return;
        }

        // ---- wave 0: the sequential scan ----
        __builtin_amdgcn_s_setprio(3);
        constexpr float L2E  = 1.4426950408889634f;
        constexpr float L2E2 = 2.8853900817779268f;
        const int j = tid;

        const float w0n = -Whh[j]       * L2E;
        const float w1n = -Whh[64 + j]  * L2E;
        const float w2s =  Whh[128 + j] * L2E2;
        const float w3n = -Whh[192 + j] * L2E;
        const float nb0 = -(bih[j]       + bhh[j])       * L2E;
        const float nb1 = -(bih[64 + j]  + bhh[64 + j])  * L2E;
        const float b2s =  (bih[128 + j] + bhh[128 + j]) * L2E2;
        const float nb3 = -(bih[192 + j] + bhh[192 + j]) * L2E;
        const float whr = Whr[j];

        float h = 0.0f, c = 0.0f, vp = 0.0f;
        float r0[8], r1[8], r2[8], r3[8];

        for (int cc = 0; cc < NCH; ++cc) {
            const float* buf = (cc & 1) ? gbuf1 : gbuf0;
            float* cb = ((cc & 1) ? cbuf1 : cbuf0) + j;
            // prefetch depth-8 ring (static offsets)
            #pragma unroll
            for (int q = 0; q < 8; ++q) {
                const float* Bp = buf + q * 256 + j;
                r0[q] = Bp[0]; r1[q] = Bp[64]; r2[q] = Bp[128]; r3[q] = Bp[192];
            }
            #pragma unroll
            for (int s = 0; s < CH; ++s) {
                const int q = s & 7;
                const float pre0 = fmaf(r0[q], -L2E,  nb0);
                const float pre1 = fmaf(r1[q], -L2E,  nb1);
                const float pre2 = fmaf(r2[q],  L2E2, b2s);
                const float pre3 = fmaf(r3[q], -L2E,  nb3);
                const float xi = fmaf(w0n, h, pre0);
                const float xf = fmaf(w1n, h, pre1);
                const float xg = fmaf(w2s, h, pre2);
                const float xo = fmaf(w3n, h, pre3);
                const float si_ = RCPF(1.0f + EXP2(xi));
                const float sf  = RCPF(1.0f + EXP2(xf));
                const float tg  = fmaf(-2.0f, RCPF(1.0f + EXP2(xg)), 1.0f);
                const float so  = RCPF(1.0f + EXP2(xo));
                c = fmaf(sf, c, si_ * tg);
                cb[s * 64] = c;                       // ds_write, static offset
                const float tc = fmaf(-2.0f, RCPF(1.0f + EXP2(c * L2E2)), 1.0f);
                float hv = tc * (so * whr);
                hv = dpp_sum64_lane63(hv);
                h = readlane63(hv);
                vp = (j == ((cc * CH + s) & 63)) ? h : vp;
                if (s < CH - 8) {                     // refill ring, static offsets
                    const float* Bp = buf + (s + 8) * 256 + j;
                    r0[q] = Bp[0]; r1[q] = Bp[64]; r2[q] = Bp[128]; r3[q] = Bp[192];
                }
            }
            if (cc & 1) p[(cc - 1) * CH + j] = vp;    // coalesced, every 64 steps
            __syncthreads();
        }
        return;
    }

    float (*As)[68] = reinterpret_cast<float(*)[68]>(smem);
    float (*Bs)[68] = reinterpret_cast<float(*)[68]>(smem + 16 * 68);
    const int bid = blockIdx.x - 1;
    const int tx = threadIdx.x & 15, ty = threadIdx.x >> 4;
    if (bid < 2048) {                      // fore tiles: 256 x 8
        const int bm = (bid >> 3) * 64, bn = (bid & 7) * 64;
        float acc[4][4] = {};
        gemm_tile_acc<true>(x, Weff, 512, 512, bm, bn, As, Bs, acc);
        #pragma unroll
        for (int i = 0; i < 4; ++i)
            #pragma unroll
            for (int j = 0; j < 4; ++j)
                fore[(size_t)(bm + ty * 4 + i) * 512 + bn + tx * 4 + j] =
                    acc[i][j] + beff[bn + tx * 4 + j];
    } else {                               // Gf tiles: 64 x 4
        const int t = bid - 2048;
        const int bm = (t >> 2) * 64, bn = (t & 3) * 64;
        float acc[4][4] = {};
        gemm_tile_acc<true>(x, Wg, 512, 256, bm, bn, As, Bs, acc);
        #pragma unroll
        for (int i = 0; i < 4; ++i)
            #pragma unroll
            for (int j = 0; j < 4; ++j)
                Gf[(size_t)(bm + ty * 4 + i) * 256 + bn + tx * 4 + j] = acc[i][j];
    }
}

// ---------------------------------------------------------------------------
// finish: blocks [0,64) forecast cells (+ forecast broadcast; gates need +bf2);
//         blocks [64,128) progress broadcast
// ---------------------------------------------------------------------------
__global__ __launch_bounds__(256) void finish_kernel(
    const float* __restrict__ Gf, const float* __restrict__ bf2,
    const float* __restrict__ Whh, const float* __restrict__ bih,
    const float* __restrict__ bhh, const float* __restrict__ Whr,
    const float* __restrict__ c_hist, const float* __restrict__ p,
    float* __restrict__ out)
{
    constexpr int S = 4096, BS = 4 * 4096;
    const int bid = blockIdx.x;
    if (bid < 64) {
        const int w = threadIdx.x >> 6, j = threadIdx.x & 63;
        const float bi0 = bf2[j]       + bih[j]       + bhh[j];
        const float bi1 = bf2[64 + j]  + bih[64 + j]  + bhh[64 + j];
        const float bi2 = bf2[128 + j] + bih[128 + j] + bhh[128 + j];
        const float bi3 = bf2[192 + j] + bih[192 + j] + bhh[192 + j];
        for (int o = 0; o < 16; ++o) {
            const int t = bid * 64 + w * 16 + o;
            const float h2 = p[t];
            const float c2 = c_hist[(size_t)t * 64 + j];
            const float* G = Gf + (size_t)t * 256;
            const float gi = G[j]       + bi0 + Whh[j] * h2;
            const float gf = G[64 + j]  + bi1 + Whh[64 + j] * h2;
            const float gg = G[128 + j] + bi2 + Whh[128 + j] * h2;
            const float go = G[192 + j] + bi3 + Whh[192 + j] * h2;
            const float cf = fsig(gf) * c2 + fsig(gi) * ftanh(gg);
            float hv = fsig(go) * ftanh(cf) * Whr[j];
            hv = dpp_sum64_lane63(hv);
            if (j == 63) {
                out[BS + 0 * S + t] = hv;
                out[BS + 1 * S + t] = hv;
                out[BS + 2 * S + t] = hv;
                out[BS + 3 * S + t] = hv;
            }
        }
    } else {
        const int i = (bid - 64) * 256 + threadIdx.x;  // 0..16383
        out[i] = p[i & (S - 1)];
    }
}

extern "C" void kernel_launch(void* const* d_in, const int* in_sizes, int n_in,
                              void* d_out, int out_size, void* d_ws, size_t ws_size,
                              hipStream_t stream) {
    const float* x   = (const float*)d_in[0];
    const float* W1  = (const float*)d_in[1];
    const float* b1  = (const float*)d_in[2];
    const float* W2  = (const float*)d_in[3];
    const float* b2  = (const float*)d_in[4];
    const float* Wih = (const float*)d_in[5];
    const float* Whh = (const float*)d_in[6];
    const float* bih = (const float*)d_in[7];
    const float* bhh = (const float*)d_in[8];
    const float* Whr = (const float*)d_in[9];
    float* out = (float*)d_out;

    constexpr int Bb = 4, S = 4096;
    const int M = Bb * S; // 16384

    float* ws     = (float*)d_ws;
    float* Weff   = ws;                       // 512*512
    float* beff   = Weff + 512 * 512;         // 512
    float* Gx     = beff + 512;               // 4096*256
    float* Gf     = Gx + S * 256;             // 4096*256
    float* c_hist = Gf + S * 256;             // 4096*64
    float* p      = c_hist + S * 64;          // 4096
    float* Wg     = p + S;                    // 256*512
    float* bf2    = Wg + 256 * 512;           // 256

    float* fore = out + 2 * M;                // (16384,512) region of d_out

    // 1) Weff/beff/Gx (all independent)
    prep_kernel<<<328, 256, 0, stream>>>(x, W1, b1, W2, b2, Wih, Weff, beff, Gx);

    // 2) Wg = Wih@Weff, bf2 = Wih@beff
    wg_kernel<<<33, 256, 0, stream>>>(Wih, Weff, beff, Wg, bf2);

    // 3) scan (block 0, LDS-staged, depth-8 ring) || fore GEMM || Gf GEMM
    scanfore_kernel<<<2305, 256, 0, stream>>>(
        x, Weff, beff, Gx, Wg, Whh, bih, bhh, Whr, c_hist, p, fore, Gf);

    // 4) forecast cells + output broadcasts
    finish_kernel<<<128, 256, 0, stream>>>(
        Gf, bf2, Whh, bih, bhh, Whr, c_hist, p, out);
}

// Round 7
// 674.598 us; speedup vs baseline: 2.6137x; 1.0430x over previous
//
#include <hip/hip_runtime.h>
#include <hip/hip_bf16.h>

// B=4, S=4096, D=512, FH=2048, H=64
// outputs: progress (B*S) ++ forecast (B*S) ++ fore (B*S*D), all f32

#if __has_builtin(__builtin_amdgcn_exp2f)
__device__ __forceinline__ float EXP2(float x) { return __builtin_amdgcn_exp2f(x); }
#else
__device__ __forceinline__ float EXP2(float x) { return __expf(x * 0.6931471805599453f); }
#endif
#if __has_builtin(__builtin_amdgcn_rcpf)
__device__ __forceinline__ float RCPF(float x) { return __builtin_amdgcn_rcpf(x); }
#else
__device__ __forceinline__ float RCPF(float x) { return 1.0f / x; }
#endif

__device__ __forceinline__ float fsig(float x) { return 1.0f / (1.0f + __expf(-x)); }
__device__ __forceinline__ float ftanh(float x) { return 1.0f - 2.0f / (1.0f + __expf(2.0f * x)); }

// Wave64 sum via DPP row_shr 1/2/4/8 + row_bcast15/31; full sum lands in lane 63.
__device__ __forceinline__ float dpp_sum64_lane63(float x) {
    x += __int_as_float(__builtin_amdgcn_update_dpp(0, __float_as_int(x), 0x111, 0xf, 0xf, true));
    x += __int_as_float(__builtin_amdgcn_update_dpp(0, __float_as_int(x), 0x112, 0xf, 0xf, true));
    x += __int_as_float(__builtin_amdgcn_update_dpp(0, __float_as_int(x), 0x114, 0xf, 0xf, true));
    x += __int_as_float(__builtin_amdgcn_update_dpp(0, __float_as_int(x), 0x118, 0xf, 0xf, true));
    x += __int_as_float(__builtin_amdgcn_update_dpp(0, __float_as_int(x), 0x142, 0xf, 0xf, true));
    x += __int_as_float(__builtin_amdgcn_update_dpp(0, __float_as_int(x), 0x143, 0xf, 0xf, true));
    return x;
}
__device__ __forceinline__ float readlane63(float x) {
    return __int_as_float(__builtin_amdgcn_readlane(__float_as_int(x), 63));
}

constexpr float L2E  = 1.4426950408889634f;  // log2(e)
constexpr float L2E2 = 2.8853900817779268f;  // 2*log2(e)

// ---------------------------------------------------------------------------
// 64x64 f32 tile core (BK=16): fills acc[4][4] for tile (bm,bn).
//   BT=true : B is [N][K] row-major  -> C = A @ B^T
//   BT=false: B is [K][N] row-major  -> C = A @ B
// ---------------------------------------------------------------------------
template<bool BT>
__device__ void gemm_tile_acc(const float* __restrict__ A, const float* __restrict__ B,
                              int K, int N, int bm, int bn,
                              float (* __restrict__ As)[68], float (* __restrict__ Bs)[68],
                              float acc[4][4])
{
    const int tid = threadIdx.x;
    const int tx = tid & 15, ty = tid >> 4;
    for (int k0 = 0; k0 < K; k0 += 16) {
        {
            const int r = tid >> 2, cc = (tid & 3) * 4;
            const float4 av = *reinterpret_cast<const float4*>(
                &A[(size_t)(bm + r) * K + k0 + cc]);
            As[cc + 0][r] = av.x; As[cc + 1][r] = av.y;
            As[cc + 2][r] = av.z; As[cc + 3][r] = av.w;
        }
        if (BT) {
            const int r = tid >> 2, cc = (tid & 3) * 4;
            const float4 bv = *reinterpret_cast<const float4*>(
                &B[(size_t)(bn + r) * K + k0 + cc]);
            Bs[cc + 0][r] = bv.x; Bs[cc + 1][r] = bv.y;
            Bs[cc + 2][r] = bv.z; Bs[cc + 3][r] = bv.w;
        } else {
            const int r = tid >> 4, cc = (tid & 15) * 4;
            const float4 bv = *reinterpret_cast<const float4*>(
                &B[(size_t)(k0 + r) * N + bn + cc]);
            Bs[r][cc + 0] = bv.x; Bs[r][cc + 1] = bv.y;
            Bs[r][cc + 2] = bv.z; Bs[r][cc + 3] = bv.w;
        }
        __syncthreads();
        #pragma unroll
        for (int k = 0; k < 16; ++k) {
            float a[4], b[4];
            #pragma unroll
            for (int i = 0; i < 4; ++i) a[i] = As[k][ty * 4 + i];
            #pragma unroll
            for (int j = 0; j < 4; ++j) b[j] = Bs[k][tx * 4 + j];
            #pragma unroll
            for (int i = 0; i < 4; ++i)
                #pragma unroll
                for (int j = 0; j < 4; ++j)
                    acc[i][j] = fmaf(a[i], b[j], acc[i][j]);
        }
        __syncthreads();
    }
}

// ---------------------------------------------------------------------------
// prep: blocks [0,64) Weff = W2@W1 ; [64,72) beff = W2@b1+b2 ; [72,328) Gx
// Gx epilogue pre-folds the gate scale and bias:
//   gate i,f,o: Gx' = -L2E  * (G + bih+bhh)
//   gate g    : Gx' =  L2E2 * (G + bih+bhh)
// ---------------------------------------------------------------------------
__global__ __launch_bounds__(256) void prep_kernel(
    const float* __restrict__ x, const float* __restrict__ W1,
    const float* __restrict__ b1, const float* __restrict__ W2,
    const float* __restrict__ b2, const float* __restrict__ Wih,
    const float* __restrict__ bih, const float* __restrict__ bhh,
    float* __restrict__ Weff, float* __restrict__ beff, float* __restrict__ Gx)
{
    __shared__ float As[16][68], Bs[16][68];
    const int bid = blockIdx.x;
    const int tx = threadIdx.x & 15, ty = threadIdx.x >> 4;

    if (bid < 64) {                       // Weff: M=N=512, K=2048, B=[K][N]
        const int bm = (bid >> 3) * 64, bn = (bid & 7) * 64;
        float acc[4][4] = {};
        gemm_tile_acc<false>(W2, W1, 2048, 512, bm, bn, As, Bs, acc);
        #pragma unroll
        for (int i = 0; i < 4; ++i)
            #pragma unroll
            for (int j = 0; j < 4; ++j)
                Weff[(size_t)(bm + ty * 4 + i) * 512 + bn + tx * 4 + j] = acc[i][j];
    } else if (bid < 72) {                // beff
        const int w = threadIdx.x >> 6, j = threadIdx.x & 63;
        const int base = (bid - 64) * 64 + w * 16;
        for (int o = 0; o < 16; ++o) {
            const int i = base + o;
            float s = 0.0f;
            #pragma unroll
            for (int m = 0; m < 32; ++m)
                s = fmaf(W2[(size_t)i * 2048 + j + 64 * m], b1[j + 64 * m], s);
            s = dpp_sum64_lane63(s);
            if (j == 63) beff[i] = s + b2[i];
        }
    } else {                              // Gx: M=4096, N=256, K=512, B=[N][K]
        const int b = bid - 72;
        const int bm = (b >> 2) * 64, bn = (b & 3) * 64;
        float acc[4][4] = {};
        gemm_tile_acc<true>(x, Wih, 512, 256, bm, bn, As, Bs, acc);
        #pragma unroll
        for (int i = 0; i < 4; ++i)
            #pragma unroll
            for (int j = 0; j < 4; ++j) {
                const int col = bn + tx * 4 + j;
                const float sc = ((col >> 6) == 2) ? L2E2 : -L2E;
                const float bb = sc * (bih[col] + bhh[col]);
                Gx[(size_t)(bm + ty * 4 + i) * 256 + col] =
                    fmaf(acc[i][j], sc, bb);
            }
    }
}

// ---------------------------------------------------------------------------
// wg: blocks [0,32) Wg = Wih @ Weff (256x512, K=512); block 32: bf2 = Wih @ beff
// ---------------------------------------------------------------------------
__global__ __launch_bounds__(256) void wg_kernel(
    const float* __restrict__ Wih, const float* __restrict__ Weff,
    const float* __restrict__ beff, float* __restrict__ Wg, float* __restrict__ bf2)
{
    __shared__ float As[16][68], Bs[16][68];
    const int bid = blockIdx.x;
    if (bid < 32) {                        // M=256 (4 tiles), N=512 (8 tiles)
        const int bm = (bid >> 3) * 64, bn = (bid & 7) * 64;
        const int tx = threadIdx.x & 15, ty = threadIdx.x >> 4;
        float acc[4][4] = {};
        gemm_tile_acc<false>(Wih, Weff, 512, 512, bm, bn, As, Bs, acc);
        #pragma unroll
        for (int i = 0; i < 4; ++i)
            #pragma unroll
            for (int j = 0; j < 4; ++j)
                Wg[(size_t)(bm + ty * 4 + i) * 512 + bn + tx * 4 + j] = acc[i][j];
    } else {                               // bf2: 4 waves x 64 outputs
        const int w = threadIdx.x >> 6, j = threadIdx.x & 63;
        for (int o = 0; o < 64; ++o) {
            const int i = w * 64 + o;
            float s = 0.0f;
            #pragma unroll
            for (int m = 0; m < 8; ++m)
                s = fmaf(Wih[(size_t)i * 512 + j + 64 * m], beff[j + 64 * m], s);
            s = dpp_sum64_lane63(s);
            if (j == 63) bf2[i] = s;
        }
    }
}

// ---------------------------------------------------------------------------
// scanfore: block 0 = LDS-staged scan. Wave0 scans with a CONTINUOUS depth-8
//   register ring (barrier mid-chunk; steps 24-31 refill from the next
//   buffer, so the ring never drains). c_hist goes out via global stores
//   (vmcnt; the lgkm queue holds only ring ds_reads). Waves 1-3 stream Gx.
// blocks [1,2049) fore = x @ Weff^T + beff; [2049,2305) Gf = x @ Wg^T.
// ---------------------------------------------------------------------------
__global__ __launch_bounds__(256) void scanfore_kernel(
    const float* __restrict__ x, const float* __restrict__ Weff,
    const float* __restrict__ beff, const float* __restrict__ Gx,
    const float* __restrict__ Wg,
    const float* __restrict__ Whh, const float* __restrict__ bih,
    const float* __restrict__ bhh, const float* __restrict__ Whr,
    float* __restrict__ c_hist, float* __restrict__ p,
    float* __restrict__ fore, float* __restrict__ Gf)
{
    // LDS: gbufA[8192] | gbufB[8192] floats = 64 KB. GEMM blocks alias front.
    __shared__ __align__(16) float smem[16384];
    constexpr int S = 4096, CH = 32, NCH = S / CH;      // 128 chunks

    if (blockIdx.x == 0) {
        const int tid = threadIdx.x;
        float* gbufA = smem;
        float* gbufB = smem + 8192;

        // prologue: all 256 threads load chunk 0 into gbufA (2048 float4)
        {
            const float4* src = reinterpret_cast<const float4*>(Gx);
            float4* dst = reinterpret_cast<float4*>(gbufA);
            #pragma unroll
            for (int u = 0; u < 8; ++u) dst[tid + u * 256] = src[tid + u * 256];
        }
        __syncthreads();

        if (tid >= 64) {
            // ---- loader waves ----
            const int lt = tid - 64;  // 0..191
            auto fill = [&](float* dstf, int chunk) {
                const float4* src = reinterpret_cast<const float4*>(
                    Gx + (size_t)chunk * CH * 256);
                float4* dst = reinterpret_cast<float4*>(dstf);
                float4 tmp[11];
                #pragma unroll
                for (int u = 0; u < 11; ++u) {
                    const int idx = lt + u * 192;
                    if (idx < 2048) tmp[u] = src[idx];
                }
                #pragma unroll
                for (int u = 0; u < 11; ++u) {
                    const int idx = lt + u * 192;
                    if (idx < 2048) dst[idx] = tmp[u];
                }
            };
            fill(gbufB, 1);                       // chunk 1 before barrier #0
            for (int cc = 0; cc < NCH; ++cc) {
                __syncthreads();                  // barrier #cc: buf (cc&1) released
                if (cc + 2 < NCH) fill((cc & 1) ? gbufB : gbufA, cc + 2);
            }
            return;
        }

        // ---- wave 0: the sequential scan ----
        __builtin_amdgcn_s_setprio(3);
        const int j = tid;

        const float w0n = -Whh[j]       * L2E;
        const float w1n = -Whh[64 + j]  * L2E;
        const float w2s =  Whh[128 + j] * L2E2;
        const float w3n = -Whh[192 + j] * L2E;
        const float whr = Whr[j];

        float h = 0.0f, c = 0.0f, vp = 0.0f;
        float r0[8], r1[8], r2[8], r3[8];
        // initial ring: slots 0..7 from gbufA
        #pragma unroll
        for (int q = 0; q < 8; ++q) {
            const float* Bp = gbufA + q * 256 + j;
            r0[q] = Bp[0]; r1[q] = Bp[64]; r2[q] = Bp[128]; r3[q] = Bp[192];
        }

#define LSTM_STEP(S_, RP)                                                     \
    {                                                                         \
        const int q = (S_) & 7;                                               \
        const float xi = fmaf(w0n, h, r0[q]);                                 \
        const float xf = fmaf(w1n, h, r1[q]);                                 \
        const float xg = fmaf(w2s, h, r2[q]);                                 \
        const float xo = fmaf(w3n, h, r3[q]);                                 \
        const float si_ = RCPF(1.0f + EXP2(xi));                              \
        const float sf  = RCPF(1.0f + EXP2(xf));                              \
        const float tg  = fmaf(-2.0f, RCPF(1.0f + EXP2(xg)), 1.0f);           \
        const float so  = RCPF(1.0f + EXP2(xo));                              \
        c = fmaf(sf, c, si_ * tg);                                            \
        c_hist[(size_t)(cc * CH + (S_)) * 64 + j] = c;                        \
        const float tc = fmaf(-2.0f, RCPF(1.0f + EXP2(c * L2E2)), 1.0f);      \
        float hv = tc * (so * whr);                                           \
        hv = dpp_sum64_lane63(hv);                                            \
        h = readlane63(hv);                                                   \
        vp = (j == ((cc * CH + (S_)) & 63)) ? h : vp;                         \
        { const float* Bp = (RP);                                             \
          r0[q] = Bp[0]; r1[q] = Bp[64]; r2[q] = Bp[128]; r3[q] = Bp[192]; }  \
    }
#define LSTM_STEP_NR(S_)                                                      \
    {                                                                         \
        const int q = (S_) & 7;                                               \
        const float xi = fmaf(w0n, h, r0[q]);                                 \
        const float xf = fmaf(w1n, h, r1[q]);                                 \
        const float xg = fmaf(w2s, h, r2[q]);                                 \
        const float xo = fmaf(w3n, h, r3[q]);                                 \
        const float si_ = RCPF(1.0f + EXP2(xi));                              \
        const float sf  = RCPF(1.0f + EXP2(xf));                              \
        const float tg  = fmaf(-2.0f, RCPF(1.0f + EXP2(xg)), 1.0f);           \
        const float so  = RCPF(1.0f + EXP2(xo));                              \
        c = fmaf(sf, c, si_ * tg);                                            \
        c_hist[(size_t)(cc * CH + (S_)) * 64 + j] = c;                        \
        const float tc = fmaf(-2.0f, RCPF(1.0f + EXP2(c * L2E2)), 1.0f);      \
        float hv = tc * (so * whr);                                           \
        hv = dpp_sum64_lane63(hv);                                            \
        h = readlane63(hv);                                                   \
        vp = (j == ((cc * CH + (S_)) & 63)) ? h : vp;                         \
    }

        for (int cc = 0; cc < NCH; ++cc) {
            const float* bufC = (cc & 1) ? gbufB : gbufA;
            const float* bufN = (cc & 1) ? gbufA : gbufB;
            #pragma unroll
            for (int s = 0; s < 24; ++s)
                LSTM_STEP(s, bufC + (s + 8) * 256 + j);
            __syncthreads();                      // barrier #cc
            if (cc + 1 < NCH) {
                #pragma unroll
                for (int s = 24; s < 32; ++s)
                    LSTM_STEP(s, bufN + (s - 24) * 256 + j);
            } else {
                #pragma unroll
                for (int s = 24; s < 32; ++s)
                    LSTM_STEP_NR(s);
            }
            if (cc & 1) p[(cc - 1) * CH + j] = vp;  // coalesced, every 64 steps
        }
#undef LSTM_STEP
#undef LSTM_STEP_NR
        return;
    }

    float (*As)[68] = reinterpret_cast<float(*)[68]>(smem);
    float (*Bs)[68] = reinterpret_cast<float(*)[68]>(smem + 16 * 68);
    const int bid = blockIdx.x - 1;
    const int tx = threadIdx.x & 15, ty = threadIdx.x >> 4;
    if (bid < 2048) {                      // fore tiles: 256 x 8
        const int bm = (bid >> 3) * 64, bn = (bid & 7) * 64;
        float acc[4][4] = {};
        gemm_tile_acc<true>(x, Weff, 512, 512, bm, bn, As, Bs, acc);
        #pragma unroll
        for (int i = 0; i < 4; ++i)
            #pragma unroll
            for (int j = 0; j < 4; ++j)
                fore[(size_t)(bm + ty * 4 + i) * 512 + bn + tx * 4 + j] =
                    acc[i][j] + beff[bn + tx * 4 + j];
    } else {                               // Gf tiles: 64 x 4
        const int t = bid - 2048;
        const int bm = (t >> 2) * 64, bn = (t & 3) * 64;
        float acc[4][4] = {};
        gemm_tile_acc<true>(x, Wg, 512, 256, bm, bn, As, Bs, acc);
        #pragma unroll
        for (int i = 0; i < 4; ++i)
            #pragma unroll
            for (int j = 0; j < 4; ++j)
                Gf[(size_t)(bm + ty * 4 + i) * 256 + bn + tx * 4 + j] = acc[i][j];
    }
}

// ---------------------------------------------------------------------------
// finish: blocks [0,64) forecast cells (+ forecast broadcast; gates need +bf2);
//         blocks [64,128) progress broadcast
// ---------------------------------------------------------------------------
__global__ __launch_bounds__(256) void finish_kernel(
    const float* __restrict__ Gf, const float* __restrict__ bf2,
    const float* __restrict__ Whh, const float* __restrict__ bih,
    const float* __restrict__ bhh, const float* __restrict__ Whr,
    const float* __restrict__ c_hist, const float* __restrict__ p,
    float* __restrict__ out)
{
    constexpr int S = 4096, BS = 4 * 4096;
    const int bid = blockIdx.x;
    if (bid < 64) {
        const int w = threadIdx.x >> 6, j = threadIdx.x & 63;
        const float bi0 = bf2[j]       + bih[j]       + bhh[j];
        const float bi1 = bf2[64 + j]  + bih[64 + j]  + bhh[64 + j];
        const float bi2 = bf2[128 + j] + bih[128 + j] + bhh[128 + j];
        const float bi3 = bf2[192 + j] + bih[192 + j] + bhh[192 + j];
        for (int o = 0; o < 16; ++o) {
            const int t = bid * 64 + w * 16 + o;
            const float h2 = p[t];
            const float c2 = c_hist[(size_t)t * 64 + j];
            const float* G = Gf + (size_t)t * 256;
            const float gi = G[j]       + bi0 + Whh[j] * h2;
            const float gf = G[64 + j]  + bi1 + Whh[64 + j] * h2;
            const float gg = G[128 + j] + bi2 + Whh[128 + j] * h2;
            const float go = G[192 + j] + bi3 + Whh[192 + j] * h2;
            const float cf = fsig(gf) * c2 + fsig(gi) * ftanh(gg);
            float hv = fsig(go) * ftanh(cf) * Whr[j];
            hv = dpp_sum64_lane63(hv);
            if (j == 63) {
                out[BS + 0 * S + t] = hv;
                out[BS + 1 * S + t] = hv;
                out[BS + 2 * S + t] = hv;
                out[BS + 3 * S + t] = hv;
            }
        }
    } else {
        const int i = (bid - 64) * 256 + threadIdx.x;  // 0..16383
        out[i] = p[i & (S - 1)];
    }
}

extern "C" void kernel_launch(void* const* d_in, const int* in_sizes, int n_in,
                              void* d_out, int out_size, void* d_ws, size_t ws_size,
                              hipStream_t stream) {
    const float* x   = (const float*)d_in[0];
    const float* W1  = (const float*)d_in[1];
    const float* b1  = (const float*)d_in[2];
    const float* W2  = (const float*)d_in[3];
    const float* b2  = (const float*)d_in[4];
    const float* Wih = (const float*)d_in[5];
    const float* Whh = (const float*)d_in[6];
    const float* bih = (const float*)d_in[7];
    const float* bhh = (const float*)d_in[8];
    const float* Whr = (const float*)d_in[9];
    float* out = (float*)d_out;

    constexpr int Bb = 4, S = 4096;
    const int M = Bb * S; // 16384

    float* ws     = (float*)d_ws;
    float* Weff   = ws;                       // 512*512
    float* beff   = Weff + 512 * 512;         // 512
    float* Gx     = beff + 512;               // 4096*256 (pre-scaled gates)
    float* Gf     = Gx + S * 256;             // 4096*256
    float* c_hist = Gf + S * 256;             // 4096*64
    float* p      = c_hist + S * 64;          // 4096
    float* Wg     = p + S;                    // 256*512
    float* bf2    = Wg + 256 * 512;           // 256

    float* fore = out + 2 * M;                // (16384,512) region of d_out

    // 1) Weff/beff/Gx (all independent)
    prep_kernel<<<328, 256, 0, stream>>>(
        x, W1, b1, W2, b2, Wih, bih, bhh, Weff, beff, Gx);

    // 2) Wg = Wih@Weff, bf2 = Wih@beff
    wg_kernel<<<33, 256, 0, stream>>>(Wih, Weff, beff, Wg, bf2);

    // 3) scan (block 0) || fore GEMM || Gf GEMM
    scanfore_kernel<<<2305, 256, 0, stream>>>(
        x, Weff, beff, Gx, Wg, Whh, bih, bhh, Whr, c_hist, p, fore, Gf);

    // 4) forecast cells + output broadcasts
    finish_kernel<<<128, 256, 0, stream>>>(
        Gf, bf2, Whh, bih, bhh, Whr, c_hist, p, out);
}